// Round 9
// baseline (99.511 us; speedup 1.0000x reference)
//
#include <hip/hip_runtime.h>

#define BQ 32
#define H  128
#define C  512
#define D  128

typedef _Float16 half8v __attribute__((ext_vector_type(8)));
typedef float floatx4 __attribute__((ext_vector_type(4)));

// ---------------------------------------------------------------------------
// Kernel 0: Q fp32 -> fp16 fragments for 16x16x32 MFMA B-operand, plus zero
// the loss accumulator (d_out).
// Frag index (half8 units): ((b*4 + kb)*2 + sh)*64 + lane
//   elem[n = lane&15][k = kb*32 + (lane>>4)*8 + j],  s = sh*16 + n
// ---------------------------------------------------------------------------
__global__ __launch_bounds__(256) void qprep_kernel(const float* __restrict__ q,
                                                    _Float16* __restrict__ qs,
                                                    float* __restrict__ out) {
  int t = blockIdx.x * 256 + threadIdx.x;     // 0..16383, one half8 frag each
  if (t == 0) out[0] = 0.0f;
  int lane = t & 63;
  int sh   = (t >> 6) & 1;
  int kb   = (t >> 7) & 3;
  int b    = t >> 9;
  int s    = sh * 16 + (lane & 15);
  int h    = kb * 32 + (lane >> 4) * 8;
  const float* src = q + ((b * 32 + s) * H + h);
  float4 v0 = *(const float4*)src;
  float4 v1 = *(const float4*)(src + 4);
  half8v o = { (_Float16)v0.x, (_Float16)v0.y, (_Float16)v0.z, (_Float16)v0.w,
               (_Float16)v1.x, (_Float16)v1.y, (_Float16)v1.z, (_Float16)v1.w };
  *(half8v*)(qs + (size_t)t * 8) = o;
}

// ---------------------------------------------------------------------------
// Kernel 1: grid 1024 = (c, b-half). Block (256 thr, 4 waves) computes
// scores[b][c] for b in [bh*16, bh*16+16).
// 16x16x32 f16 MFMA, transposed: A = P_c (m = d), B = Q_b (n = s).
// Wave w: d-half dq=w&1 (64 rows = 4 m-tiles), s-half sh=w>>1 (16 cols).
// TRUE prefetch distance 2: qb[0,1] preloaded; iteration lb issues the load
// of lb+2 into qb[(lb+2)%3] BEFORE computing lb (~a full iteration of slack).
// 3 blocks/CU via __launch_bounds__(256,3) -> 12 waves/CU latency hiding.
// P_c A-frags register-resident (64 VGPRs).
// ---------------------------------------------------------------------------
__global__ __launch_bounds__(256, 3) void scores_kernel(const float* __restrict__ pos,
                                                        const _Float16* __restrict__ qs,
                                                        float* __restrict__ scores) {
  const int c    = blockIdx.x >> 1;
  const int bh   = blockIdx.x & 1;       // b-half: b = bh*16 + lb
  const int tid  = threadIdx.x;
  const int w    = tid >> 6;
  const int lane = tid & 63;
  const int dq   = w & 1;                // d-half
  const int sh   = w >> 1;               // s-half
  const int quad = lane >> 4;
  const int nrow = lane & 15;

  __shared__ float pmm[16][4][16];       // [lb][wave][s_local]  4 KB

  const half8v* qf = (const half8v*)qs;
  const float*  pc = pos + (size_t)c * (D * H);
  const int     b0 = bh * 16;

  half8v  pa[4][4];    // P_c A-frags [mt][kb]  (64 VGPRs)
  half8v  qb[3][4];    // Q B-frags, triple-buffered [buf][kb] (48 VGPRs)
  floatx4 acc[2][4];   // [buf][mt] (32 VGPRs)
  floatx4 zc = {0.f, 0.f, 0.f, 0.f};   // persistent zero C-operand

  // P_c A-frags: A[m = dq*64 + mt*16 + nrow][k = kb*32 + quad*8 + j]
#pragma unroll
  for (int kb = 0; kb < 4; ++kb)
#pragma unroll
    for (int mt = 0; mt < 4; ++mt) {
      const float* src = pc + ((dq * 64 + mt * 16 + nrow) * H + kb * 32 + quad * 8);
      float4 v0 = *(const float4*)src;
      float4 v1 = *(const float4*)(src + 4);
      half8v f = { (_Float16)v0.x, (_Float16)v0.y, (_Float16)v0.z, (_Float16)v0.w,
                   (_Float16)v1.x, (_Float16)v1.y, (_Float16)v1.z, (_Float16)v1.w };
      pa[mt][kb] = f;
    }

  // Q fragments for lb=0,1 (global b0, b0+1)
#pragma unroll
  for (int kb = 0; kb < 4; ++kb) qb[0][kb] = qf[((b0 * 4 + kb) * 2 + sh) * 64 + lane];
#pragma unroll
  for (int kb = 0; kb < 4; ++kb) qb[1][kb] = qf[(((b0 + 1) * 4 + kb) * 2 + sh) * 64 + lane];

  // Reduce: max over this wave's 64 d-rows for each of its 16 s.
  // C/D: col s_local = lane&15, row d_local = quad*4 + r  [m89/m91]
  auto reduce_store = [&](int lb, floatx4 (&a)[4]) {
    float m0 = fmaxf(fmaxf(a[0][0], a[0][1]), fmaxf(a[0][2], a[0][3]));
    float m1 = fmaxf(fmaxf(a[1][0], a[1][1]), fmaxf(a[1][2], a[1][3]));
    float m2 = fmaxf(fmaxf(a[2][0], a[2][1]), fmaxf(a[2][2], a[2][3]));
    float m3 = fmaxf(fmaxf(a[3][0], a[3][1]), fmaxf(a[3][2], a[3][3]));
    float m  = fmaxf(fmaxf(m0, m1), fmaxf(m2, m3));
    m = fmaxf(m, __shfl_xor(m, 16));
    m = fmaxf(m, __shfl_xor(m, 32));
    if (lane < 16) pmm[lb][w][lane] = m;
  };

  // main loop: prefetch lb+2, compute lb, reduce lb-1
#pragma unroll
  for (int lb = 0; lb < 16; ++lb) {
    const int cur = lb & 1;
    if (lb + 2 < 16) {
      const int gb = b0 + lb + 2;
      half8v* dst = qb[(lb + 2) % 3];
#pragma unroll
      for (int kb = 0; kb < 4; ++kb) dst[kb] = qf[((gb * 4 + kb) * 2 + sh) * 64 + lane];
    }
    const half8v* qc = qb[lb % 3];
#pragma unroll
    for (int mt = 0; mt < 4; ++mt)
      acc[cur][mt] = __builtin_amdgcn_mfma_f32_16x16x32_f16(pa[mt][0], qc[0], zc, 0, 0, 0);
#pragma unroll
    for (int kb = 1; kb < 4; ++kb)
#pragma unroll
      for (int mt = 0; mt < 4; ++mt)
        acc[cur][mt] = __builtin_amdgcn_mfma_f32_16x16x32_f16(pa[mt][kb], qc[kb], acc[cur][mt], 0, 0, 0);
    if (lb > 0) reduce_store(lb - 1, acc[cur ^ 1]);
  }
  reduce_store(15, acc[1]);   // lb=15 landed in acc[1]

  __syncthreads();

  // epilogue: scores[b][c] = 50 * sum_s max over the two d-half waves
  // 16 lb x 8 threads (4 s each); sum over all 8 threads: xor 1,2,4.
  if (tid < 128) {
    int lb = tid >> 3;
    int t8 = tid & 7;
    float v = 0.f;
#pragma unroll
    for (int j = 0; j < 4; ++j) {
      int s  = t8 * 4 + j;
      int h2 = s >> 4, sl = s & 15;
      v += fmaxf(pmm[lb][2 * h2][sl], pmm[lb][2 * h2 + 1][sl]);
    }
    v += __shfl_xor(v, 1);
    v += __shfl_xor(v, 2);
    v += __shfl_xor(v, 4);
    if (t8 == 0) scores[(b0 + lb) * C + c] = v * 50.0f;   // / TEMPERATURE
  }
}

// ---------------------------------------------------------------------------
// Kernel 2: one block per b; loss += (logsumexp_c - scores[b][0]) / 32
// ---------------------------------------------------------------------------
__global__ __launch_bounds__(256) void loss_kernel(const float* __restrict__ scores,
                                                   float* __restrict__ out) {
  __shared__ float red[8];
  const int b = blockIdx.x, tid = threadIdx.x, w = tid >> 6, lane = tid & 63;
  const float* row = scores + b * C;
  float x0 = row[tid], x1 = row[tid + 256];
  float mx = fmaxf(x0, x1);
#pragma unroll
  for (int off = 1; off < 64; off <<= 1) mx = fmaxf(mx, __shfl_xor(mx, off));
  if (lane == 0) red[w] = mx;
  __syncthreads();
  float bmax = fmaxf(fmaxf(red[0], red[1]), fmaxf(red[2], red[3]));
  float e = __expf(x0 - bmax) + __expf(x1 - bmax);
#pragma unroll
  for (int off = 1; off < 64; off <<= 1) e += __shfl_xor(e, off);
  if (lane == 0) red[4 + w] = e;
  __syncthreads();
  if (tid == 0) {
    float s = red[4] + red[5] + red[6] + red[7];
    atomicAdd(out, (bmax + __logf(s) - row[0]) * (1.0f / 32.0f));
  }
}

extern "C" void kernel_launch(void* const* d_in, const int* in_sizes, int n_in,
                              void* d_out, int out_size, void* d_ws, size_t ws_size,
                              hipStream_t stream) {
  const float* q = (const float*)d_in[0];   // [32,32,128] fp32
  const float* p = (const float*)d_in[1];   // [512,128,128] fp32
  float* scores  = (float*)d_ws;                              // 64 KB
  _Float16* qs   = (_Float16*)((char*)d_ws + 65536);          // 256 KB fp16 frags

  qprep_kernel<<<64, 256, 0, stream>>>(q, qs, (float*)d_out);
  scores_kernel<<<2 * C, 256, 0, stream>>>(p, qs, scores);
  loss_kernel<<<32, 256, 0, stream>>>(scores, (float*)d_out);
}

// Round 10
// 92.886 us; speedup vs baseline: 1.0713x; 1.0713x over previous
//
#include <hip/hip_runtime.h>

#define BQ 32
#define H  128
#define C  512
#define D  128

typedef _Float16 half8v __attribute__((ext_vector_type(8)));
typedef float floatx4 __attribute__((ext_vector_type(4)));

// ---------------------------------------------------------------------------
// Kernel 0: Q fp32 -> fp16 fragments for 16x16x32 MFMA B-operand, plus zero
// the loss accumulator (d_out).
// Frag index (half8 units): ((b*4 + kb)*2 + sh)*64 + lane
//   elem[n = lane&15][k = kb*32 + (lane>>4)*8 + j],  s = sh*16 + n
// ---------------------------------------------------------------------------
__global__ __launch_bounds__(256) void qprep_kernel(const float* __restrict__ q,
                                                    _Float16* __restrict__ qs,
                                                    float* __restrict__ out) {
  int t = blockIdx.x * 256 + threadIdx.x;     // 0..16383, one half8 frag each
  if (t == 0) out[0] = 0.0f;
  int lane = t & 63;
  int sh   = (t >> 6) & 1;
  int kb   = (t >> 7) & 3;
  int b    = t >> 9;
  int s    = sh * 16 + (lane & 15);
  int h    = kb * 32 + (lane >> 4) * 8;
  const float* src = q + ((b * 32 + s) * H + h);
  float4 v0 = *(const float4*)src;
  float4 v1 = *(const float4*)(src + 4);
  half8v o = { (_Float16)v0.x, (_Float16)v0.y, (_Float16)v0.z, (_Float16)v0.w,
               (_Float16)v1.x, (_Float16)v1.y, (_Float16)v1.z, (_Float16)v1.w };
  *(half8v*)(qs + (size_t)t * 8) = o;
}

// ---------------------------------------------------------------------------
// Kernel 1: block c (256 thr, 4 waves) -> scores[b][c].  [r7 base config]
// 16x16x32 f16 MFMA, transposed: A = P_c (m = d), B = Q_b (n = s).
// Wave w: d-half dq=w&1 (64 rows = 4 m-tiles), s-half sh=w>>1 (16 cols).
// SINGLE CHANGE vs r7: Q prefetch distance 1 -> 2 (qb[3] round-robin, fully
// unrolled so all register-array indices are compile-time constants).
// grid 512, __launch_bounds__(256,2): 2 blocks/CU, 2 waves/SIMD, no spill.
// ---------------------------------------------------------------------------
__global__ __launch_bounds__(256, 2) void scores_kernel(const float* __restrict__ pos,
                                                        const _Float16* __restrict__ qs,
                                                        float* __restrict__ scores) {
  const int c    = blockIdx.x;
  const int tid  = threadIdx.x;
  const int w    = tid >> 6;
  const int lane = tid & 63;
  const int dq   = w & 1;            // d-half
  const int sh   = w >> 1;           // s-half
  const int quad = lane >> 4;
  const int nrow = lane & 15;

  __shared__ float pmm[BQ][4][16];   // [b][wave][s_local]  8 KB

  const half8v* qf = (const half8v*)qs;
  const float*  pc = pos + (size_t)c * (D * H);

  half8v  pa[4][4];    // P_c A-frags [mt][kb]  (64 VGPRs)
  half8v  qb[3][4];    // Q B-frags, round-robin, prefetch distance 2 (48 VGPRs)
  floatx4 acc[2][4];   // [buf][mt] (32 VGPRs)
  floatx4 zc = {0.f, 0.f, 0.f, 0.f};   // persistent zero C-operand

  // P_c A-frags: A[m = dq*64 + mt*16 + nrow][k = kb*32 + quad*8 + j]
#pragma unroll
  for (int kb = 0; kb < 4; ++kb)
#pragma unroll
    for (int mt = 0; mt < 4; ++mt) {
      const float* src = pc + ((dq * 64 + mt * 16 + nrow) * H + kb * 32 + quad * 8);
      float4 v0 = *(const float4*)src;
      float4 v1 = *(const float4*)(src + 4);
      half8v f = { (_Float16)v0.x, (_Float16)v0.y, (_Float16)v0.z, (_Float16)v0.w,
                   (_Float16)v1.x, (_Float16)v1.y, (_Float16)v1.z, (_Float16)v1.w };
      pa[mt][kb] = f;
    }

  // Q fragments for b=0,1 (prefetch pipeline primed to depth 2)
#pragma unroll
  for (int kb = 0; kb < 4; ++kb) qb[0][kb] = qf[(kb * 2 + sh) * 64 + lane];
#pragma unroll
  for (int kb = 0; kb < 4; ++kb) qb[1][kb] = qf[((4 + kb) * 2 + sh) * 64 + lane];

  // Reduce: max over this wave's 64 d-rows for each of its 16 s.
  // C/D: col s_local = lane&15, row d_local = quad*4 + r  [m89/m91]
  auto reduce_store = [&](int b, floatx4 (&a)[4]) {
    float m0 = fmaxf(fmaxf(a[0][0], a[0][1]), fmaxf(a[0][2], a[0][3]));
    float m1 = fmaxf(fmaxf(a[1][0], a[1][1]), fmaxf(a[1][2], a[1][3]));
    float m2 = fmaxf(fmaxf(a[2][0], a[2][1]), fmaxf(a[2][2], a[2][3]));
    float m3 = fmaxf(fmaxf(a[3][0], a[3][1]), fmaxf(a[3][2], a[3][3]));
    float m  = fmaxf(fmaxf(m0, m1), fmaxf(m2, m3));
    m = fmaxf(m, __shfl_xor(m, 16));
    m = fmaxf(m, __shfl_xor(m, 32));
    if (lane < 16) pmm[b][w][lane] = m;
  };

  // main loop: prefetch b+2 (distance 2), compute b, reduce b-1
#pragma unroll
  for (int b = 0; b < BQ; ++b) {
    const int cur = b & 1;
    if (b + 2 < BQ) {
      half8v* dst = qb[(b + 2) % 3];
#pragma unroll
      for (int kb = 0; kb < 4; ++kb) dst[kb] = qf[(((b + 2) * 4 + kb) * 2 + sh) * 64 + lane];
    }
    const half8v* qc = qb[b % 3];
#pragma unroll
    for (int mt = 0; mt < 4; ++mt)
      acc[cur][mt] = __builtin_amdgcn_mfma_f32_16x16x32_f16(pa[mt][0], qc[0], zc, 0, 0, 0);
#pragma unroll
    for (int kb = 1; kb < 4; ++kb)
#pragma unroll
      for (int mt = 0; mt < 4; ++mt)
        acc[cur][mt] = __builtin_amdgcn_mfma_f32_16x16x32_f16(pa[mt][kb], qc[kb], acc[cur][mt], 0, 0, 0);
    if (b > 0) reduce_store(b - 1, acc[cur ^ 1]);
  }
  reduce_store(BQ - 1, acc[1]);   // b=31 landed in acc[1]

  __syncthreads();

  // epilogue: scores[b][c] = 50 * sum_s max over the two d-half waves
  {
    int b  = tid >> 3;
    int t8 = tid & 7;
    float v = 0.f;
#pragma unroll
    for (int j = 0; j < 4; ++j) {
      int s  = t8 * 4 + j;
      int h2 = s >> 4, sl = s & 15;
      v += fmaxf(pmm[b][2 * h2][sl], pmm[b][2 * h2 + 1][sl]);
    }
    v += __shfl_xor(v, 1);
    v += __shfl_xor(v, 2);
    v += __shfl_xor(v, 4);
    if (t8 == 0) scores[b * C + c] = v * 50.0f;   // / TEMPERATURE
  }
}

// ---------------------------------------------------------------------------
// Kernel 2: one block per b; loss += (logsumexp_c - scores[b][0]) / 32
// ---------------------------------------------------------------------------
__global__ __launch_bounds__(256) void loss_kernel(const float* __restrict__ scores,
                                                   float* __restrict__ out) {
  __shared__ float red[8];
  const int b = blockIdx.x, tid = threadIdx.x, w = tid >> 6, lane = tid & 63;
  const float* row = scores + b * C;
  float x0 = row[tid], x1 = row[tid + 256];
  float mx = fmaxf(x0, x1);
#pragma unroll
  for (int off = 1; off < 64; off <<= 1) mx = fmaxf(mx, __shfl_xor(mx, off));
  if (lane == 0) red[w] = mx;
  __syncthreads();
  float bmax = fmaxf(fmaxf(red[0], red[1]), fmaxf(red[2], red[3]));
  float e = __expf(x0 - bmax) + __expf(x1 - bmax);
#pragma unroll
  for (int off = 1; off < 64; off <<= 1) e += __shfl_xor(e, off);
  if (lane == 0) red[4 + w] = e;
  __syncthreads();
  if (tid == 0) {
    float s = red[4] + red[5] + red[6] + red[7];
    atomicAdd(out, (bmax + __logf(s) - row[0]) * (1.0f / 32.0f));
  }
}

extern "C" void kernel_launch(void* const* d_in, const int* in_sizes, int n_in,
                              void* d_out, int out_size, void* d_ws, size_t ws_size,
                              hipStream_t stream) {
  const float* q = (const float*)d_in[0];   // [32,32,128] fp32
  const float* p = (const float*)d_in[1];   // [512,128,128] fp32
  float* scores  = (float*)d_ws;                              // 64 KB
  _Float16* qs   = (_Float16*)((char*)d_ws + 65536);          // 256 KB fp16 frags

  qprep_kernel<<<64, 256, 0, stream>>>(q, qs, (float*)d_out);
  scores_kernel<<<C, 256, 0, stream>>>(p, qs, scores);
  loss_kernel<<<32, 256, 0, stream>>>(scores, (float*)d_out);
}